// Round 1
// baseline (178.059 us; speedup 1.0000x reference)
//
#include <hip/hip_runtime.h>
#include <math.h>

#if defined(__has_builtin)
#  if __has_builtin(__builtin_amdgcn_exp2f)
#    define EXP2F(x) __builtin_amdgcn_exp2f(x)
#  endif
#  if __has_builtin(__builtin_amdgcn_rcpf)
#    define RCPF(x) __builtin_amdgcn_rcpf(x)
#  endif
#endif
#ifndef EXP2F
#  define EXP2F(x) exp2f(x)
#endif
#ifndef RCPF
#  define RCPF(x) (1.0f/(x))
#endif

static constexpr int Bn = 16, QN = 512, KN = 512, Hn = 64, DV = 256, DIN = 256;
static constexpr int TQ = 8;                       // q-rows per block
static constexpr float TWO_LOG2E = 2.8853900817779268f;  // 2*log2(e)
static constexpr float LOG2E     = 1.4426950408889634f;

// out = X @ W^T.  X:[B*N, 256], W:[64,256].
// transposed=0: out[row][h]  (qproj [B,Q,64])
// transposed=1: out[b][h][r] (kprojT [B,64,K]) for coalesced k-reads later.
__global__ __launch_bounds__(256) void proj_kernel(
    const float* __restrict__ X, const float* __restrict__ W,
    float* __restrict__ out, int transposed)
{
  __shared__ __align__(16) float xs[DIN];
  __shared__ __align__(16) float red[Hn * 4];
  int row = blockIdx.x;            // global row in [0, B*512)
  int t = threadIdx.x;
  xs[t] = X[(size_t)row * DIN + t];
  __syncthreads();
  int h = t >> 2, part = t & 3;    // 4 partial lanes per output h
  const float* wrow = W + h * DIN;
  float acc = 0.f;
  // part-interleaved so the 4 parts hit distinct LDS banks (conflict-free)
  #pragma unroll
  for (int j = 0; j < 16; ++j) {
    int i = part * 4 + j * 16;
    float4 w4 = *(const float4*)(wrow + i);
    float4 x4 = *(const float4*)(xs + i);
    acc += w4.x * x4.x + w4.y * x4.y + w4.z * x4.z + w4.w * x4.w;
  }
  red[h * 4 + part] = acc;
  __syncthreads();
  if (t < Hn) {
    float4 r4 = *(const float4*)(red + t * 4);
    float s = r4.x + r4.y + r4.z + r4.w;
    int b = row >> 9, r = row & (QN - 1);
    if (transposed) out[((size_t)b * Hn + t) * KN + r] = s;
    else            out[(size_t)row * Hn + t] = s;
  }
}

// Fused additive attention: scores + masked softmax + PV.
// tanh(q+k) = 1 - 2/(Eq*Ek + 1) with Eq=exp2(C*q), Ek=exp2(C*k):
// inner element = fma + rcp + fma (1 transcendental instead of a full tanh).
__global__ __launch_bounds__(256) void attn_kernel(
    const float* __restrict__ qproj,   // [B,512,64]
    const float* __restrict__ kprojT,  // [B,64,512]
    const float* __restrict__ values,  // [B,512,256]
    const int*   __restrict__ valid_lens,
    const float* __restrict__ wv,      // [64]
    float* __restrict__ out)           // [B,512,256]
{
  __shared__ __align__(16) float qe[TQ * Hn];   // exp2(C*q)
  __shared__ __align__(16) float wv2[Hn];       // 2*wv
  __shared__ __align__(16) float pt[KN][12];    // transposed probs, stride 12 keeps 16B align
  __shared__ float inv_s[TQ];

  int t = threadIdx.x;
  int b = blockIdx.x >> 6;                 // 64 q-tiles per batch
  int q0 = (blockIdx.x & 63) * TQ;
  int L = valid_lens[b];                   // uniform per batch; skip masked k entirely

  {
    const float* qp = qproj + ((size_t)b * QN + q0) * Hn;
    qe[t]       = EXP2F(qp[t]       * TWO_LOG2E);
    qe[t + 256] = EXP2F(qp[t + 256] * TWO_LOG2E);
  }
  if (t < Hn) wv2[t] = 2.0f * wv[t];
  __syncthreads();

  float S = 0.f;                           // sum_h wv[h], hoisted out of inner loop
  #pragma unroll 8
  for (int h = 0; h < Hn; ++h) S += wv2[h];
  S *= 0.5f;

  // ---- score phase: thread owns k = t and t+256 ----
  const float* kp = kprojT + (size_t)b * Hn * KN;
  #pragma unroll
  for (int kk = 0; kk < 2; ++kk) {
    int k = t + kk * 256;
    if (k < L) {
      float acc[TQ];
      #pragma unroll
      for (int r = 0; r < TQ; ++r) acc[r] = S;
      #pragma unroll 4
      for (int h = 0; h < Hn; ++h) {
        float kv = kp[(size_t)h * KN + k];     // coalesced: lanes = consecutive k
        float ek = EXP2F(kv * TWO_LOG2E);
        float w2 = wv2[h];
        #pragma unroll
        for (int r = 0; r < TQ; ++r) {
          float d = qe[r * Hn + h] * ek + 1.0f;   // v_fma
          acc[r] -= w2 * RCPF(d);                 // v_rcp + v_fma
        }
      }
      *(float4*)&pt[k][0] = make_float4(acc[0], acc[1], acc[2], acc[3]);
      *(float4*)&pt[k][4] = make_float4(acc[4], acc[5], acc[6], acc[7]);
    }
  }
  __syncthreads();

  // ---- softmax over k<L: wave w handles rows w and w+4 ----
  int lane = t & 63, wave = t >> 6;
  #pragma unroll
  for (int rr = 0; rr < 2; ++rr) {
    int r = wave + rr * 4;
    float sv[8];
    float m = -3.0e38f;
    #pragma unroll
    for (int j = 0; j < 8; ++j) {
      int k = lane + j * 64;
      sv[j] = (k < L) ? pt[k][r] : -3.0e38f;
      m = fmaxf(m, sv[j]);
    }
    #pragma unroll
    for (int off = 32; off > 0; off >>= 1) m = fmaxf(m, __shfl_xor(m, off, 64));
    float sum = 0.f;
    #pragma unroll
    for (int j = 0; j < 8; ++j) {
      int k = lane + j * 64;
      if (k < L) {
        float p = EXP2F((sv[j] - m) * LOG2E);
        pt[k][r] = p;                        // unnormalized; 1/sum folded into epilogue
        sum += p;
      }
    }
    #pragma unroll
    for (int off = 32; off > 0; off >>= 1) sum += __shfl_xor(sum, off, 64);
    if (lane == 0) inv_s[r] = 1.0f / sum;
  }
  __syncthreads();

  // ---- PV phase: thread owns output column v = t ----
  float acc[TQ];
  #pragma unroll
  for (int r = 0; r < TQ; ++r) acc[r] = 0.f;
  const float* vb = values + (size_t)b * KN * DV + t;
  #pragma unroll 4
  for (int k = 0; k < L; ++k) {
    float val = vb[(size_t)k * DV];          // coalesced
    float4 pa = *(const float4*)&pt[k][0];   // b128 broadcast
    float4 pb = *(const float4*)&pt[k][4];
    acc[0] += pa.x * val; acc[1] += pa.y * val;
    acc[2] += pa.z * val; acc[3] += pa.w * val;
    acc[4] += pb.x * val; acc[5] += pb.y * val;
    acc[6] += pb.z * val; acc[7] += pb.w * val;
  }
  float* ob = out + ((size_t)b * QN + q0) * DV + t;
  #pragma unroll
  for (int r = 0; r < TQ; ++r) ob[(size_t)r * DV] = acc[r] * inv_s[r];
}

extern "C" void kernel_launch(void* const* d_in, const int* in_sizes, int n_in,
                              void* d_out, int out_size, void* d_ws, size_t ws_size,
                              hipStream_t stream) {
  const float* queries    = (const float*)d_in[0];
  const float* keys       = (const float*)d_in[1];
  const float* values     = (const float*)d_in[2];
  const int*   valid_lens = (const int*)d_in[3];
  const float* Wq         = (const float*)d_in[4];
  const float* Wk         = (const float*)d_in[5];
  const float* wv         = (const float*)d_in[6];
  float* out = (float*)d_out;

  float* qproj  = (float*)d_ws;                       // [B,512,64]  = 2 MB
  float* kprojT = qproj + (size_t)Bn * QN * Hn;       // [B,64,512]  = 2 MB

  proj_kernel<<<Bn * QN, 256, 0, stream>>>(queries, Wq, qproj, 0);
  proj_kernel<<<Bn * KN, 256, 0, stream>>>(keys,    Wk, kprojT, 1);
  attn_kernel<<<Bn * (QN / TQ), 256, 0, stream>>>(qproj, kprojT, values,
                                                  valid_lens, wv, out);
}

// Round 2
// 156.927 us; speedup vs baseline: 1.1347x; 1.1347x over previous
//
#include <hip/hip_runtime.h>
#include <math.h>

#if defined(__has_builtin)
#  if __has_builtin(__builtin_amdgcn_exp2f)
#    define EXP2F(x) __builtin_amdgcn_exp2f(x)
#  endif
#  if __has_builtin(__builtin_amdgcn_rcpf)
#    define RCPF(x) __builtin_amdgcn_rcpf(x)
#  endif
#endif
#ifndef EXP2F
#  define EXP2F(x) exp2f(x)
#endif
#ifndef RCPF
#  define RCPF(x) (1.0f/(x))
#endif

static constexpr int Bn = 16, QN = 512, KN = 512, Hn = 64, DV = 256, DIN = 256;
static constexpr int TQ = 8;                       // q-rows per attn block
static constexpr int PR = 32;                      // rows per proj block
static constexpr float TWO_LOG2E = 2.8853900817779268f;  // 2*log2(e)
static constexpr float LOG2E     = 1.4426950408889634f;

// Fused projection for BOTH q and k, with exp2 folded into the epilogue.
// blocks [0,256):   qe [B,512,64]  = exp2(C * queries@Wq^T)
// blocks [256,512): ekT [B,64,512] = exp2(C * keys@Wk^T), transposed for
//                   coalesced k-reads in attn.
// Each block: 32 rows x 64 cols, 4096 fma/thread, LDS-staged X chunks.
__global__ __launch_bounds__(256) void proj_kernel(
    const float* __restrict__ queries, const float* __restrict__ keys,
    const float* __restrict__ Wq, const float* __restrict__ Wk,
    float* __restrict__ qe, float* __restrict__ ekT)
{
  __shared__ __align__(16) float xs[PR][36];   // +4 pad: rotates banks, keeps 16B align (144B rows)
  int blk = blockIdx.x;
  bool is_k = blk >= 256;
  int tile = is_k ? blk - 256 : blk;
  const float* X = is_k ? keys : queries;
  const float* W = is_k ? Wk : Wq;
  int row0 = tile * PR;
  int t = threadIdx.x;
  int c = t & 63;                 // output col (h)
  int wg = t >> 6;                // wave owns rows wg*8..+7 (wave-uniform LDS broadcasts)
  float acc[8];
  #pragma unroll
  for (int i = 0; i < 8; ++i) acc[i] = 0.f;

  for (int dc = 0; dc < DIN; dc += 32) {
    __syncthreads();
    {
      int row = t >> 3, dp = t & 7;          // 32 rows x 8 float4
      float4 v = *(const float4*)(X + (size_t)(row0 + row) * DIN + dc + dp * 4);
      *(float4*)&xs[row][dp * 4] = v;
    }
    __syncthreads();
    const float* wr = W + c * DIN + dc;
    #pragma unroll
    for (int dd = 0; dd < 32; dd += 4) {
      float4 w4 = *(const float4*)(wr + dd);
      #pragma unroll
      for (int i = 0; i < 8; ++i) {
        float4 x4 = *(const float4*)&xs[wg * 8 + i][dd];  // wave-uniform -> LDS broadcast
        acc[i] += w4.x * x4.x + w4.y * x4.y + w4.z * x4.z + w4.w * x4.w;
      }
    }
  }
  #pragma unroll
  for (int i = 0; i < 8; ++i) {
    int row = row0 + wg * 8 + i;
    float e = EXP2F(acc[i] * TWO_LOG2E);
    if (!is_k) {
      qe[(size_t)row * Hn + c] = e;                       // lanes -> consecutive c, coalesced
    } else {
      int b = row >> 9, k = row & (KN - 1);
      ekT[((size_t)b * Hn + c) * KN + k] = e;             // 32 consecutive k per (c,block): 1 line
    }
  }
}

// Fused attention: scores (via tanh(q+k) = 1 - 2/(Eq*Ek+1): fma+rcp+fma per
// element, exp2 precomputed in proj) + in-register softmax sum (scores are
// bounded |s|<=sum|wv|~7, so no max-subtraction needed) + split-k PV.
// 512 threads/block doubles wave count vs 256 (grid 1024 = 32 waves/CU max).
__global__ __launch_bounds__(512) void attn_kernel(
    const float* __restrict__ qe,      // [B,512,64]  exp2(C*q)
    const float* __restrict__ ekT,     // [B,64,512]  exp2(C*k)
    const float* __restrict__ values,  // [B,512,256]
    const int*   __restrict__ valid_lens,
    const float* __restrict__ wv,      // [64]
    float* __restrict__ out)           // [B,512,256]
{
  __shared__ __align__(16) float qes[TQ * Hn];   // 2 KB
  __shared__ float wv2[Hn];
  __shared__ __align__(16) float pt[KN][12];     // 24 KB, transposed unnormalized probs
  __shared__ float wsum[8][8];                   // [wave][row] partial softmax sums
  __shared__ float inv_s[TQ];
  __shared__ __align__(16) float pacc[TQ][DV];   // 8 KB, PV half-1 partials

  int t = threadIdx.x;
  int b = blockIdx.x & 15;                 // batch b -> XCD b%8: values/ekT stay in one L2
  int q0 = (blockIdx.x >> 4) * TQ;
  int L = valid_lens[b];                   // uniform per batch; masked k skipped entirely
  int lane = t & 63, wave = t >> 6;

  qes[t] = qe[((size_t)b * QN + q0) * Hn + t];
  if (t < Hn) wv2[t] = 2.0f * wv[t];
  __syncthreads();

  float S = 0.f;                           // sum_h wv[h], hoisted out of the inner loop
  #pragma unroll
  for (int h = 0; h < Hn; ++h) S += wv2[h];
  S *= 0.5f;

  // ---- score phase: thread owns k = t ----
  {
    int k = t;
    float sc[TQ];
    #pragma unroll
    for (int r = 0; r < TQ; ++r) sc[r] = S;
    if (k < L) {
      const float* kp = ekT + (size_t)b * Hn * KN + k;
      #pragma unroll 4
      for (int h = 0; h < Hn; ++h) {
        float ek = kp[(size_t)h * KN];     // coalesced: lanes = consecutive k
        float w2 = wv2[h];
        #pragma unroll
        for (int r = 0; r < TQ; ++r) {
          float d = qes[r * Hn + h] * ek + 1.0f;   // v_fma
          sc[r] -= w2 * RCPF(d);                   // v_rcp + v_fma
        }
      }
    }
    float p[TQ];
    #pragma unroll
    for (int r = 0; r < TQ; ++r) p[r] = (k < L) ? EXP2F(sc[r] * LOG2E) : 0.f;
    if (k < L) {
      *(float4*)&pt[k][0] = make_float4(p[0], p[1], p[2], p[3]);
      *(float4*)&pt[k][4] = make_float4(p[4], p[5], p[6], p[7]);
    }
    // in-register row sums: butterfly over the wave, no separate LDS pass
    #pragma unroll
    for (int r = 0; r < TQ; ++r) {
      float s = p[r];
      #pragma unroll
      for (int off = 32; off > 0; off >>= 1) s += __shfl_xor(s, off, 64);
      if (lane == r) wsum[wave][r] = s;
    }
  }
  __syncthreads();
  if (t < TQ) {
    float s = 0.f;
    #pragma unroll
    for (int w = 0; w < 8; ++w) s += wsum[w][t];
    inv_s[t] = 1.0f / s;
  }
  __syncthreads();

  // ---- PV phase: col = t&255, k-range split in half across t>>8 ----
  int col = t & (DV - 1), half = t >> 8;
  int mid = L >> 1;
  int k0 = half ? mid : 0;
  int k1 = half ? L : mid;
  float acc[TQ];
  #pragma unroll
  for (int r = 0; r < TQ; ++r) acc[r] = 0.f;
  const float* vb = values + (size_t)b * KN * DV + col;
  #pragma unroll 4
  for (int k = k0; k < k1; ++k) {
    float val = vb[(size_t)k * DV];          // coalesced
    float4 pa = *(const float4*)&pt[k][0];   // same addr across lanes: LDS broadcast
    float4 pb = *(const float4*)&pt[k][4];
    acc[0] += pa.x * val; acc[1] += pa.y * val;
    acc[2] += pa.z * val; acc[3] += pa.w * val;
    acc[4] += pb.x * val; acc[5] += pb.y * val;
    acc[6] += pb.z * val; acc[7] += pb.w * val;
  }
  if (half) {
    #pragma unroll
    for (int r = 0; r < TQ; ++r) pacc[r][col] = acc[r];
  }
  __syncthreads();
  if (!half) {
    float* ob = out + ((size_t)b * QN + q0) * DV + col;
    #pragma unroll
    for (int r = 0; r < TQ; ++r)
      ob[(size_t)r * DV] = (acc[r] + pacc[r][col]) * inv_s[r];
  }
}

extern "C" void kernel_launch(void* const* d_in, const int* in_sizes, int n_in,
                              void* d_out, int out_size, void* d_ws, size_t ws_size,
                              hipStream_t stream) {
  const float* queries    = (const float*)d_in[0];
  const float* keys       = (const float*)d_in[1];
  const float* values     = (const float*)d_in[2];
  const int*   valid_lens = (const int*)d_in[3];
  const float* Wq         = (const float*)d_in[4];
  const float* Wk         = (const float*)d_in[5];
  const float* wv         = (const float*)d_in[6];
  float* out = (float*)d_out;

  float* qe  = (float*)d_ws;                      // [B,512,64]  = 2 MB
  float* ekT = qe + (size_t)Bn * QN * Hn;         // [B,64,512]  = 2 MB

  proj_kernel<<<512, 256, 0, stream>>>(queries, keys, Wq, Wk, qe, ekT);
  attn_kernel<<<Bn * (QN / TQ), 512, 0, stream>>>(qe, ekT, values,
                                                  valid_lens, wv, out);
}

// Round 3
// 150.296 us; speedup vs baseline: 1.1847x; 1.0441x over previous
//
#include <hip/hip_runtime.h>
#include <math.h>

#if defined(__has_builtin)
#  if __has_builtin(__builtin_amdgcn_exp2f)
#    define EXP2F(x) __builtin_amdgcn_exp2f(x)
#  endif
#  if __has_builtin(__builtin_amdgcn_rcpf)
#    define RCPF(x) __builtin_amdgcn_rcpf(x)
#  endif
#endif
#ifndef EXP2F
#  define EXP2F(x) exp2f(x)
#endif
#ifndef RCPF
#  define RCPF(x) (1.0f/(x))
#endif

static constexpr int Bn = 16, QN = 512, KN = 512, Hn = 64, DV = 256, DIN = 256;
static constexpr int TQ = 8;
static constexpr float TWO_LOG2E = 2.8853900817779268f;  // 2*log2(e)
static constexpr float LOG2E     = 1.4426950408889634f;

// Both projections, exp2 fused, BOTH outputs transposed: [B, 64, 512].
// blocks [0,128): qeT from queries/Wq; [128,256): ekT from keys/Wk.
// Block: 64 rows x 64 cols. lane = row, wave = 8 cols (wave-uniform ->
// W reads become s_load, SGPR operands: zero VALU/LDS cost on the B side).
// X staged in LDS per 128-k chunk; one ds_read_b128 feeds 32 FMAs.
__global__ __launch_bounds__(512) void proj_kernel(
    const float* __restrict__ queries, const float* __restrict__ keys,
    const float* __restrict__ Wq, const float* __restrict__ Wk,
    float* __restrict__ qeT, float* __restrict__ ekT)
{
  __shared__ __align__(16) float xs[64][132];   // 33 KB; stride 132: 16B-aligned rows, banks rotate
  int t = threadIdx.x;
  int blk = blockIdx.x;
  bool is_k = blk >= 128;
  int tile = blk & 127;
  const float* X = is_k ? keys : queries;
  const float* W = is_k ? Wk : Wq;
  int row0 = tile * 64;
  int lane = t & 63;
  int w8 = __builtin_amdgcn_readfirstlane(t >> 6);   // wave id 0..7, provably uniform
  const float* Wb = W + (size_t)w8 * 8 * DIN;        // uniform -> s_load
  float acc[8];
  #pragma unroll
  for (int j = 0; j < 8; ++j) acc[j] = 0.f;

  #pragma unroll
  for (int kc = 0; kc < 2; ++kc) {                   // two 128-wide k chunks
    __syncthreads();
    #pragma unroll
    for (int j = 0; j < 4; ++j) {                    // 2048 float4, 4 per thread, coalesced
      int idx = t + 512 * j;
      int row = idx >> 5, c4 = idx & 31;
      *(float4*)&xs[row][c4 * 4] =
          *(const float4*)(X + (size_t)(row0 + row) * DIN + kc * 128 + c4 * 4);
    }
    __syncthreads();
    const float* Wc = Wb + kc * 128;
    #pragma unroll 4
    for (int kq = 0; kq < 32; ++kq) {
      float4 x4 = *(const float4*)&xs[lane][kq * 4];     // 16 B LDS per 32 FMA
      #pragma unroll
      for (int j = 0; j < 8; ++j) {
        float4 w4 = *(const float4*)(Wc + j * DIN + kq * 4);  // uniform -> s_load_dwordx4
        acc[j] += x4.x * w4.x + x4.y * w4.y + x4.z * w4.z + x4.w * w4.w;
      }
    }
  }
  int row = row0 + lane;
  int b = row >> 9, rk = row & (KN - 1);
  float* outp = is_k ? ekT : qeT;
  #pragma unroll
  for (int j = 0; j < 8; ++j)                           // lanes -> consecutive rk: coalesced
    outp[((size_t)b * Hn + w8 * 8 + j) * KN + rk] = EXP2F(acc[j] * TWO_LOG2E);
}

// Fused attention. tanh(q+k) = 1 - 2/(Eq*Ek+1): fma+rcp+fma per element,
// exp2 folded into proj. Scores bounded (|s| <= sum|wv| ~ 7): softmax
// without max-subtraction, row sums via in-register butterfly.
// b = blockIdx>>6 so the 4 blocks landing on one CU span 4 DIFFERENT
// batches (L-imbalance averaging; b=blk&15 put the same batch 4x per CU).
__global__ __launch_bounds__(512) void attn_kernel(
    const float* __restrict__ qeT,     // [B,64,512] exp2(C*q), h-major
    const float* __restrict__ ekT,     // [B,64,512] exp2(C*k), h-major
    const float* __restrict__ values,  // [B,512,256]
    const int*   __restrict__ valid_lens,
    const float* __restrict__ wv,      // [64]
    float* __restrict__ out)           // [B,512,256]
{
  __shared__ __align__(16) float pt[KN][12];       // 24 KB transposed unnormalized probs
  __shared__ __align__(16) float pacc[3][TQ][DV];  // 24 KB PV partials (k-quarters 1..3)
  __shared__ float wsum[8][TQ];
  __shared__ float inv_s[TQ];

  int t = threadIdx.x;
  int b = blockIdx.x >> 6;
  int q0 = (blockIdx.x & 63) * TQ;
  int L = valid_lens[b];                   // uniform per batch; masked k skipped entirely
  int lane = t & 63, wave = t >> 6;

  float S = 0.f;                           // sum_h wv[h] (uniform s_loads), hoisted
  #pragma unroll
  for (int h = 0; h < Hn; ++h) S += wv[h];

  // ---- score phase: thread owns k = t; q side via wave-uniform s_load ----
  {
    int k = t;
    float sc[TQ];
    #pragma unroll
    for (int r = 0; r < TQ; ++r) sc[r] = S;
    if (k < L) {
      const float* qbase = qeT + (size_t)b * Hn * QN + q0;  // uniform
      const float* kbase = ekT + (size_t)b * Hn * KN + k;   // per-lane, coalesced
      #pragma unroll 2
      for (int h = 0; h < Hn; ++h) {
        float ek = kbase[(size_t)h * KN];
        const float* qp = qbase + (size_t)h * QN;           // uniform -> s_load_dwordx8
        float w2 = 2.0f * wv[h];
        #pragma unroll
        for (int r = 0; r < TQ; ++r) {
          float d = qp[r] * ek + 1.0f;     // v_fma (SGPR q operand)
          sc[r] -= w2 * RCPF(d);           // v_rcp + v_fma
        }
      }
    }
    float p[TQ];
    #pragma unroll
    for (int r = 0; r < TQ; ++r) p[r] = (k < L) ? EXP2F(sc[r] * LOG2E) : 0.f;
    if (k < L) {
      *(float4*)&pt[k][0] = make_float4(p[0], p[1], p[2], p[3]);
      *(float4*)&pt[k][4] = make_float4(p[4], p[5], p[6], p[7]);
    }
    #pragma unroll
    for (int r = 0; r < TQ; ++r) {         // in-register row sums, no LDS pass
      float s = p[r];
      #pragma unroll
      for (int off = 32; off > 0; off >>= 1) s += __shfl_xor(s, off, 64);
      if (lane == r) wsum[wave][r] = s;
    }
  }
  __syncthreads();
  if (t < TQ) {
    float s = 0.f;
    #pragma unroll
    for (int w = 0; w < 8; ++w) s += wsum[w][t];
    inv_s[t] = 1.0f / s;
  }
  __syncthreads();

  // ---- PV: thread owns 2 cols (float2 values) x quarter of k ----
  int p2 = t & 127, kq = t >> 7;
  int c = p2 * 2;
  int k0 = (L * kq) >> 2, k1 = (L * (kq + 1)) >> 2;
  float a0[TQ], a1[TQ];
  #pragma unroll
  for (int r = 0; r < TQ; ++r) { a0[r] = 0.f; a1[r] = 0.f; }
  const float* vb = values + (size_t)b * KN * DV + c;
  #pragma unroll 2
  for (int k = k0; k < k1; ++k) {
    float2 v2 = *(const float2*)(vb + (size_t)k * DV);  // coalesced
    float4 pa = *(const float4*)&pt[k][0];              // broadcast (same addr all lanes)
    float4 pb = *(const float4*)&pt[k][4];
    a0[0] += pa.x * v2.x; a1[0] += pa.x * v2.y;
    a0[1] += pa.y * v2.x; a1[1] += pa.y * v2.y;
    a0[2] += pa.z * v2.x; a1[2] += pa.z * v2.y;
    a0[3] += pa.w * v2.x; a1[3] += pa.w * v2.y;
    a0[4] += pb.x * v2.x; a1[4] += pb.x * v2.y;
    a0[5] += pb.y * v2.x; a1[5] += pb.y * v2.y;
    a0[6] += pb.z * v2.x; a1[6] += pb.z * v2.y;
    a0[7] += pb.w * v2.x; a1[7] += pb.w * v2.y;
  }
  if (kq) {
    #pragma unroll
    for (int r = 0; r < TQ; ++r)
      *(float2*)&pacc[kq - 1][r][c] = make_float2(a0[r], a1[r]);
  }
  __syncthreads();
  if (kq == 0) {
    float* ob = out + ((size_t)b * QN + q0) * DV + c;
    #pragma unroll
    for (int r = 0; r < TQ; ++r) {
      float s0 = a0[r], s1 = a1[r];
      #pragma unroll
      for (int q = 0; q < 3; ++q) {
        float2 pp = *(const float2*)&pacc[q][r][c];
        s0 += pp.x; s1 += pp.y;
      }
      float iv = inv_s[r];
      *(float2*)(ob + (size_t)r * DV) = make_float2(s0 * iv, s1 * iv);
    }
  }
}

extern "C" void kernel_launch(void* const* d_in, const int* in_sizes, int n_in,
                              void* d_out, int out_size, void* d_ws, size_t ws_size,
                              hipStream_t stream) {
  const float* queries    = (const float*)d_in[0];
  const float* keys       = (const float*)d_in[1];
  const float* values     = (const float*)d_in[2];
  const int*   valid_lens = (const int*)d_in[3];
  const float* Wq         = (const float*)d_in[4];
  const float* Wk         = (const float*)d_in[5];
  const float* wv         = (const float*)d_in[6];
  float* out = (float*)d_out;

  float* qeT = (float*)d_ws;                      // [B,64,512] = 2 MB
  float* ekT = qeT + (size_t)Bn * Hn * QN;        // [B,64,512] = 2 MB

  proj_kernel<<<256, 512, 0, stream>>>(queries, keys, Wq, Wk, qeT, ekT);
  attn_kernel<<<Bn * (QN / TQ), 512, 0, stream>>>(qeT, ekT, values,
                                                  valid_lens, wv, out);
}